// Round 1
// baseline (123.620 us; speedup 1.0000x reference)
//
#include <hip/hip_runtime.h>

#define NPIX   3136        // 56*56
#define MROWS  12544       // 4*3136
#define QKV_STRIDE 1605632 // MROWS*128 floats per q/k/v buffer
#define SCALE  0.17677669529663687f  // 32^-0.5

// ---------------------------------------------------------------------------
// GEMM: out = A[M][128] * W[N][128]^T + bias
// tile 64 rows x 128 cols, 128 threads, 8x8 micro-tile, K staged in 4x32 chunks
// LDS stride 36 floats (144B) -> b128 reads conflict-free (quad = (r + k/4)%8)
// EPI=0: scatter to q/k/v buffers [which][b][head][pix][32]
// EPI=1: plain write out[row][col]
// ---------------------------------------------------------------------------
template<int EPI>
__global__ __launch_bounds__(128)
void gemm_k(const float* __restrict__ A, const float* __restrict__ W,
            const float* __restrict__ bias, float* __restrict__ out)
{
    const int row0 = blockIdx.x * 64;
    const int col0 = blockIdx.y * 128;
    const int t  = threadIdx.x;
    const int tx = t & 15;      // 0..15
    const int ty = t >> 4;      // 0..7

    __shared__ float As[64 * 36];
    __shared__ float Ws[128 * 36];

    float acc[8][8];
#pragma unroll
    for (int i = 0; i < 8; ++i)
#pragma unroll
        for (int j = 0; j < 8; ++j) acc[i][j] = 0.f;

#pragma unroll 1
    for (int kc = 0; kc < 4; ++kc) {
        __syncthreads();
        // stage A tile: 64 rows x 32 k   (512 float4s / 128 threads = 4 each)
#pragma unroll
        for (int it = 0; it < 4; ++it) {
            int idx = t + it * 128;
            int r  = idx >> 3;
            int k0 = (idx & 7) << 2;
            float4 v = *reinterpret_cast<const float4*>(
                A + (size_t)(row0 + r) * 128 + kc * 32 + k0);
            *reinterpret_cast<float4*>(&As[r * 36 + k0]) = v;
        }
        // stage W tile: 128 rows x 32 k  (1024 float4s / 128 threads = 8 each)
#pragma unroll
        for (int it = 0; it < 8; ++it) {
            int idx = t + it * 128;
            int c  = idx >> 3;
            int k0 = (idx & 7) << 2;
            float4 v = *reinterpret_cast<const float4*>(
                W + (size_t)(col0 + c) * 128 + kc * 32 + k0);
            *reinterpret_cast<float4*>(&Ws[c * 36 + k0]) = v;
        }
        __syncthreads();

#pragma unroll
        for (int k4 = 0; k4 < 32; k4 += 4) {
            float4 a[8], b[8];
#pragma unroll
            for (int i = 0; i < 8; ++i)
                a[i] = *reinterpret_cast<const float4*>(&As[(ty + 8 * i) * 36 + k4]);
#pragma unroll
            for (int j = 0; j < 8; ++j)
                b[j] = *reinterpret_cast<const float4*>(&Ws[(tx + 16 * j) * 36 + k4]);
#pragma unroll
            for (int i = 0; i < 8; ++i)
#pragma unroll
                for (int j = 0; j < 8; ++j) {
                    acc[i][j] += a[i].x * b[j].x;
                    acc[i][j] += a[i].y * b[j].y;
                    acc[i][j] += a[i].z * b[j].z;
                    acc[i][j] += a[i].w * b[j].w;
                }
        }
    }

#pragma unroll
    for (int i = 0; i < 8; ++i) {
        int row = row0 + ty + 8 * i;
        int b_  = row / NPIX;
        int pix = row - b_ * NPIX;
#pragma unroll
        for (int j = 0; j < 8; ++j) {
            int col = col0 + tx + 16 * j;
            float val = acc[i][j] + bias[col];
            if (EPI == 1) {
                out[(size_t)row * 128 + col] = val;
            } else {
                int which = col >> 7;          // 0=q 1=k 2=v
                int head  = (col & 127) >> 5;
                int d     = col & 31;
                out[(size_t)which * QKV_STRIDE +
                    ((size_t)(b_ * 4 + head) * NPIX + pix) * 32 + d] = val;
            }
        }
    }
}

// ---------------------------------------------------------------------------
// Neighborhood attention: one 64-thread block per (8x8 pixel tile, head, batch)
// K (then V, reusing LDS) staged as [196][32] with T2 XOR swizzle
// (float_off = d0 ^ ((nb&7)<<2)) so fixed-d reads across the 8x8 pixel grid
// spread over all 8 bank-quads. OOB neighbors stay zero -> logit = bias only,
// kept in softmax (matches reference zero-padding semantics).
// ---------------------------------------------------------------------------
__global__ __launch_bounds__(64)
void natten_k(const float* __restrict__ qb, const float* __restrict__ kb,
              const float* __restrict__ vb, const float* __restrict__ rpb,
              float* __restrict__ att)
{
    const int tile = blockIdx.x;          // 0..48
    const int h    = blockIdx.y;          // 0..3
    const int b    = blockIdx.z;          // 0..3
    const int ti = (tile / 7) * 8;
    const int tj = (tile % 7) * 8;
    const int t  = threadIdx.x;
    const int pi = t >> 3;                // 0..7
    const int pj = t & 7;                 // 0..7

    __shared__ float kvs[196 * 32];       // 25088 B, K then V

    const size_t hb = (size_t)(b * 4 + h) * NPIX * 32;
    const float* kbase = kb + hb;
    const float* vbase = vb + hb;

    // ---- stage K (coalesced: 8 lanes cover one pixel's 128B row) ----
    for (int e = t; e < 196 * 8; e += 64) {
        int p  = e >> 3;
        int d0 = (e & 7) << 2;
        int wi = p / 14;
        int wj = p - wi * 14;
        int gi = ti - 3 + wi;
        int gj = tj - 3 + wj;
        bool ok = (gi >= 0) && (gi < 56) && (gj >= 0) && (gj < 56);
        float4 kv = make_float4(0.f, 0.f, 0.f, 0.f);
        if (ok) kv = *reinterpret_cast<const float4*>(kbase + (gi * 56 + gj) * 32 + d0);
        *reinterpret_cast<float4*>(&kvs[p * 32 + (d0 ^ ((p & 7) << 2))]) = kv;
    }

    // ---- load q while K staging is in flight ----
    const int pix = (ti + pi) * 56 + (tj + pj);
    const float* qsrc = qb + hb + (size_t)pix * 32;
    float4 qv[8];
#pragma unroll
    for (int d4 = 0; d4 < 8; ++d4)
        qv[d4] = *reinterpret_cast<const float4*>(qsrc + d4 * 4);

    __syncthreads();

    // ---- QK^T + bias ----
    float logits[49];
    float m = -1e30f;
    const float* bias = rpb + h * 169;
#pragma unroll
    for (int ki = 0; ki < 7; ++ki) {
#pragma unroll
        for (int kj = 0; kj < 7; ++kj) {
            int nb   = (pi + ki) * 14 + (pj + kj);
            int base = nb * 32;
            int swx  = (nb & 7) << 2;
            float s = 0.f;
#pragma unroll
            for (int d4 = 0; d4 < 8; ++d4) {
                float4 kf = *reinterpret_cast<const float4*>(&kvs[base + ((d4 << 2) ^ swx)]);
                float4 qf = qv[d4];
                s += qf.x * kf.x + qf.y * kf.y + qf.z * kf.z + qf.w * kf.w;
            }
            float lg = s * SCALE + bias[(ki + 3) * 13 + (kj + 3)];
            logits[ki * 7 + kj] = lg;
            m = fmaxf(m, lg);
        }
    }

    // ---- softmax ----
    float sum = 0.f;
#pragma unroll
    for (int n = 0; n < 49; ++n) {
        float e = __expf(logits[n] - m);
        logits[n] = e;
        sum += e;
    }
    float inv = 1.f / sum;

    // ---- stage V into the same LDS ----
    __syncthreads();   // everyone done reading K
    for (int e = t; e < 196 * 8; e += 64) {
        int p  = e >> 3;
        int d0 = (e & 7) << 2;
        int wi = p / 14;
        int wj = p - wi * 14;
        int gi = ti - 3 + wi;
        int gj = tj - 3 + wj;
        bool ok = (gi >= 0) && (gi < 56) && (gj >= 0) && (gj < 56);
        float4 vv = make_float4(0.f, 0.f, 0.f, 0.f);
        if (ok) vv = *reinterpret_cast<const float4*>(vbase + (gi * 56 + gj) * 32 + d0);
        *reinterpret_cast<float4*>(&kvs[p * 32 + (d0 ^ ((p & 7) << 2))]) = vv;
    }
    __syncthreads();

    // ---- P·V ----
    float4 o[8];
#pragma unroll
    for (int d4 = 0; d4 < 8; ++d4) o[d4] = make_float4(0.f, 0.f, 0.f, 0.f);
#pragma unroll
    for (int ki = 0; ki < 7; ++ki) {
#pragma unroll
        for (int kj = 0; kj < 7; ++kj) {
            int nb   = (pi + ki) * 14 + (pj + kj);
            int base = nb * 32;
            int swx  = (nb & 7) << 2;
            float w = logits[ki * 7 + kj];
#pragma unroll
            for (int d4 = 0; d4 < 8; ++d4) {
                float4 vf = *reinterpret_cast<const float4*>(&kvs[base + ((d4 << 2) ^ swx)]);
                o[d4].x += w * vf.x;
                o[d4].y += w * vf.y;
                o[d4].z += w * vf.z;
                o[d4].w += w * vf.w;
            }
        }
    }

    // ---- write attention output, layout [b][pix][h*32+d] for the proj GEMM ----
    float* dst = att + ((size_t)b * NPIX + pix) * 128 + h * 32;
#pragma unroll
    for (int d4 = 0; d4 < 8; ++d4) {
        float4 r;
        r.x = o[d4].x * inv; r.y = o[d4].y * inv;
        r.z = o[d4].z * inv; r.w = o[d4].w * inv;
        *reinterpret_cast<float4*>(dst + d4 * 4) = r;
    }
}

// ---------------------------------------------------------------------------
extern "C" void kernel_launch(void* const* d_in, const int* in_sizes, int n_in,
                              void* d_out, int out_size, void* d_ws, size_t ws_size,
                              hipStream_t stream)
{
    const float* x      = (const float*)d_in[0];
    const float* qkv_w  = (const float*)d_in[1];
    const float* qkv_b  = (const float*)d_in[2];
    const float* rpb    = (const float*)d_in[3];
    const float* proj_w = (const float*)d_in[4];
    const float* proj_b = (const float*)d_in[5];
    float* out = (float*)d_out;
    float* ws  = (float*)d_ws;

    // ws layout: q | k | v  (each QKV_STRIDE floats, 19.3 MB total)
    float* qbuf = ws;
    float* kbuf = ws + (size_t)QKV_STRIDE;
    float* vbuf = ws + (size_t)2 * QKV_STRIDE;
    // d_out doubles as attention-output scratch (proj blocks read only their
    // own rows, staged to LDS before epilogue writes -> no hazard)
    float* att = out;

    // 1) QKV projection: [12544,128] @ [384,128]^T, scatter into q/k/v
    dim3 g1(MROWS / 64, 3);
    gemm_k<0><<<g1, dim3(128), 0, stream>>>(x, qkv_w, qkv_b, qbuf);

    // 2) neighborhood attention
    dim3 g2(49, 4, 4);
    natten_k<<<g2, dim3(64), 0, stream>>>(qbuf, kbuf, vbuf, rpb, att);

    // 3) output projection: [12544,128] @ [128,128]^T (in-place on d_out)
    dim3 g3(MROWS / 64, 1);
    gemm_k<1><<<g3, dim3(128), 0, stream>>>(att, proj_w, proj_b, out);
}

// Round 2
// 85.765 us; speedup vs baseline: 1.4414x; 1.4414x over previous
//
#include <hip/hip_runtime.h>

#define NPIX   3136        // 56*56
#define MROWS  12544       // 4*3136
#define QKV_STRIDE 1605632 // MROWS*128 floats per q/k/v buffer
#define SCALE  0.17677669529663687f  // 32^-0.5

// sum across each aligned quad of 4 lanes via DPP quad_perm (stays on VALU,
// no LDS-pipe traffic): 0xB1 = perm[1,0,3,2] (xor 1), 0x4E = perm[2,3,0,1] (xor 2)
__device__ __forceinline__ float quad_reduce_sum(float x) {
    x += __int_as_float(__builtin_amdgcn_mov_dpp(__float_as_int(x), 0xB1, 0xF, 0xF, true));
    x += __int_as_float(__builtin_amdgcn_mov_dpp(__float_as_int(x), 0x4E, 0xF, 0xF, true));
    return x;
}

// ---------------------------------------------------------------------------
// GEMM: out = A[M][128] * W[N][128]^T + bias
// 256 threads (8 ty x 32 tx), micro-tile MI rows x NJ cols per thread.
// Tile = (8*MI) rows x (32*NJ) cols. K staged in 4 chunks of 32 with register
// prefetch of chunk kc+1 issued before the compute loop (overlaps global
// latency with FMAs). LDS stride 36 floats -> reads at/near bank floor
// (a-reads broadcast per ty; b-reads 32 distinct addrs = volume minimum).
// EPI=0: scatter to q/k/v buffers [which][b][head][pix][32]
// EPI=1: plain write out[row][col]
// ---------------------------------------------------------------------------
template<int EPI, int MI, int NJ>
__global__ __launch_bounds__(256)
void gemm_k(const float* __restrict__ A, const float* __restrict__ W,
            const float* __restrict__ bias, float* __restrict__ out)
{
    const int row0 = blockIdx.x * (8 * MI);
    const int col0 = blockIdx.y * (32 * NJ);
    const int t  = threadIdx.x;
    const int tx = t & 31;      // cols: tx + 32*j
    const int ty = t >> 5;      // rows: ty + 8*i

    __shared__ float As[8 * MI * 36];
    __shared__ float Ws[32 * NJ * 36];

    constexpr int AIT = (8 * MI * 8) / 256;   // float4s per thread for A chunk
    constexpr int WIT = NJ;                   // float4s per thread for W chunk

    float acc[MI][NJ];
#pragma unroll
    for (int i = 0; i < MI; ++i)
#pragma unroll
        for (int j = 0; j < NJ; ++j) acc[i][j] = 0.f;

    float4 pa[AIT], pw[WIT];

    // prologue: load chunk 0 into regs
#pragma unroll
    for (int it = 0; it < AIT; ++it) {
        int idx = t + it * 256;
        int r = idx >> 3, k0 = (idx & 7) << 2;
        pa[it] = *reinterpret_cast<const float4*>(A + (size_t)(row0 + r) * 128 + k0);
    }
#pragma unroll
    for (int it = 0; it < WIT; ++it) {
        int idx = t + it * 256;
        int c = idx >> 3, k0 = (idx & 7) << 2;
        pw[it] = *reinterpret_cast<const float4*>(W + (size_t)(col0 + c) * 128 + k0);
    }

#pragma unroll 1
    for (int kc = 0; kc < 4; ++kc) {
        if (kc > 0) __syncthreads();          // prev-chunk readers done
#pragma unroll
        for (int it = 0; it < AIT; ++it) {
            int idx = t + it * 256;
            int r = idx >> 3, k0 = (idx & 7) << 2;
            *reinterpret_cast<float4*>(&As[r * 36 + k0]) = pa[it];
        }
#pragma unroll
        for (int it = 0; it < WIT; ++it) {
            int idx = t + it * 256;
            int c = idx >> 3, k0 = (idx & 7) << 2;
            *reinterpret_cast<float4*>(&Ws[c * 36 + k0]) = pw[it];
        }
        __syncthreads();

        if (kc < 3) {                         // prefetch next chunk (overlapped)
#pragma unroll
            for (int it = 0; it < AIT; ++it) {
                int idx = t + it * 256;
                int r = idx >> 3, k0 = (idx & 7) << 2;
                pa[it] = *reinterpret_cast<const float4*>(
                    A + (size_t)(row0 + r) * 128 + (kc + 1) * 32 + k0);
            }
#pragma unroll
            for (int it = 0; it < WIT; ++it) {
                int idx = t + it * 256;
                int c = idx >> 3, k0 = (idx & 7) << 2;
                pw[it] = *reinterpret_cast<const float4*>(
                    W + (size_t)(col0 + c) * 128 + (kc + 1) * 32 + k0);
            }
        }

#pragma unroll
        for (int k4 = 0; k4 < 32; k4 += 4) {
            float4 a[MI], b[NJ];
#pragma unroll
            for (int i = 0; i < MI; ++i)
                a[i] = *reinterpret_cast<const float4*>(&As[(ty + 8 * i) * 36 + k4]);
#pragma unroll
            for (int j = 0; j < NJ; ++j)
                b[j] = *reinterpret_cast<const float4*>(&Ws[(tx + 32 * j) * 36 + k4]);
#pragma unroll
            for (int i = 0; i < MI; ++i)
#pragma unroll
                for (int j = 0; j < NJ; ++j) {
                    acc[i][j] += a[i].x * b[j].x;
                    acc[i][j] += a[i].y * b[j].y;
                    acc[i][j] += a[i].z * b[j].z;
                    acc[i][j] += a[i].w * b[j].w;
                }
        }
    }

#pragma unroll
    for (int i = 0; i < MI; ++i) {
        int row = row0 + ty + 8 * i;
        int b_  = row / NPIX;
        int pix = row - b_ * NPIX;
#pragma unroll
        for (int j = 0; j < NJ; ++j) {
            int col = col0 + tx + 32 * j;
            float val = acc[i][j] + bias[col];
            if (EPI == 1) {
                out[(size_t)row * 128 + col] = val;
            } else {
                int which = col >> 7;          // 0=q 1=k 2=v
                int head  = (col & 127) >> 5;
                int d     = col & 31;
                out[(size_t)which * QKV_STRIDE +
                    ((size_t)(b_ * 4 + head) * NPIX + pix) * 32 + d] = val;
            }
        }
    }
}

// ---------------------------------------------------------------------------
// Neighborhood attention: 256-thread block per (8x8 pixel tile, head, batch).
// 4 lanes per pixel-head, each owning an 8-float d-slice (quad logit reduce
// via DPP). K then V staged in the same swizzled LDS buffer
// (float_off = d0 ^ ((nb&7)<<2)). OOB neighbors stay zero -> logit = bias
// only, kept in softmax (matches reference zero-padding semantics).
// ---------------------------------------------------------------------------
__global__ __launch_bounds__(256)
void natten_k(const float* __restrict__ qb, const float* __restrict__ kb,
              const float* __restrict__ vb, const float* __restrict__ rpb,
              float* __restrict__ att)
{
    const int tile = blockIdx.x;          // 0..48
    const int h    = blockIdx.y;          // 0..3
    const int b    = blockIdx.z;          // 0..3
    const int ti = (tile / 7) * 8;
    const int tj = (tile % 7) * 8;
    const int t   = threadIdx.x;
    const int sub = t & 3;                // d-slice owner within the quad
    const int pl  = t >> 2;               // 0..63 local pixel
    const int pi  = pl >> 3;
    const int pj  = pl & 7;

    __shared__ float kvs[196 * 32];       // 25088 B, K then V

    const size_t hb = (size_t)(b * 4 + h) * NPIX * 32;
    const float* kbase = kb + hb;
    const float* vbase = vb + hb;

    // ---- stage K ----
    for (int e = t; e < 196 * 8; e += 256) {
        int p  = e >> 3;
        int d0 = (e & 7) << 2;
        int wi = p / 14;
        int wj = p - wi * 14;
        int gi = ti - 3 + wi;
        int gj = tj - 3 + wj;
        bool ok = ((unsigned)gi < 56u) && ((unsigned)gj < 56u);
        float4 kv = make_float4(0.f, 0.f, 0.f, 0.f);
        if (ok) kv = *reinterpret_cast<const float4*>(kbase + (gi * 56 + gj) * 32 + d0);
        *reinterpret_cast<float4*>(&kvs[p * 32 + (d0 ^ ((p & 7) << 2))]) = kv;
    }

    // ---- load this lane's q d-slice while K staging is in flight ----
    const int pix = (ti + pi) * 56 + (tj + pj);
    const float* qsrc = qb + hb + (size_t)pix * 32 + sub * 8;
    float4 q0 = *reinterpret_cast<const float4*>(qsrc);
    float4 q1 = *reinterpret_cast<const float4*>(qsrc + 4);

    __syncthreads();

    // ---- QK^T + bias ----
    const float* bias = rpb + h * 169;
    const int d0a = sub * 8;
    const int d0b = sub * 8 + 4;
    float logits[49];
    float m = -1e30f;
#pragma unroll
    for (int ki = 0; ki < 7; ++ki) {
#pragma unroll
        for (int kj = 0; kj < 7; ++kj) {
            int nb   = (pi + ki) * 14 + (pj + kj);
            int base = nb * 32;
            int swx  = (nb & 7) << 2;
            float4 k0 = *reinterpret_cast<const float4*>(&kvs[base + (d0a ^ swx)]);
            float4 k1 = *reinterpret_cast<const float4*>(&kvs[base + (d0b ^ swx)]);
            float s = q0.x * k0.x + q0.y * k0.y + q0.z * k0.z + q0.w * k0.w
                    + q1.x * k1.x + q1.y * k1.y + q1.z * k1.z + q1.w * k1.w;
            s = quad_reduce_sum(s);           // full 32-d dot, all 4 lanes
            float lg = s * SCALE + bias[(ki + 3) * 13 + (kj + 3)];
            logits[ki * 7 + kj] = lg;
            m = fmaxf(m, lg);
        }
    }

    // ---- softmax (redundant per quad lane; cheap) ----
    float sum = 0.f;
#pragma unroll
    for (int n = 0; n < 49; ++n) {
        float e = __expf(logits[n] - m);
        logits[n] = e;
        sum += e;
    }
    float inv = 1.f / sum;

    // ---- stage V into the same LDS ----
    __syncthreads();   // everyone done reading K
    for (int e = t; e < 196 * 8; e += 256) {
        int p  = e >> 3;
        int d0 = (e & 7) << 2;
        int wi = p / 14;
        int wj = p - wi * 14;
        int gi = ti - 3 + wi;
        int gj = tj - 3 + wj;
        bool ok = ((unsigned)gi < 56u) && ((unsigned)gj < 56u);
        float4 vv = make_float4(0.f, 0.f, 0.f, 0.f);
        if (ok) vv = *reinterpret_cast<const float4*>(vbase + (gi * 56 + gj) * 32 + d0);
        *reinterpret_cast<float4*>(&kvs[p * 32 + (d0 ^ ((p & 7) << 2))]) = vv;
    }
    __syncthreads();

    // ---- P·V (each lane accumulates its own 8-float d-slice) ----
    float4 o0 = make_float4(0.f, 0.f, 0.f, 0.f);
    float4 o1 = make_float4(0.f, 0.f, 0.f, 0.f);
#pragma unroll
    for (int ki = 0; ki < 7; ++ki) {
#pragma unroll
        for (int kj = 0; kj < 7; ++kj) {
            int nb   = (pi + ki) * 14 + (pj + kj);
            int base = nb * 32;
            int swx  = (nb & 7) << 2;
            float w = logits[ki * 7 + kj];
            float4 v0 = *reinterpret_cast<const float4*>(&kvs[base + (d0a ^ swx)]);
            float4 v1 = *reinterpret_cast<const float4*>(&kvs[base + (d0b ^ swx)]);
            o0.x += w * v0.x; o0.y += w * v0.y; o0.z += w * v0.z; o0.w += w * v0.w;
            o1.x += w * v1.x; o1.y += w * v1.y; o1.z += w * v1.z; o1.w += w * v1.w;
        }
    }

    // ---- write attention output, layout [b][pix][h*32+d] for the proj GEMM ----
    float* dst = att + ((size_t)b * NPIX + pix) * 128 + h * 32 + sub * 8;
    float4 r0, r1;
    r0.x = o0.x * inv; r0.y = o0.y * inv; r0.z = o0.z * inv; r0.w = o0.w * inv;
    r1.x = o1.x * inv; r1.y = o1.y * inv; r1.z = o1.z * inv; r1.w = o1.w * inv;
    *reinterpret_cast<float4*>(dst)     = r0;
    *reinterpret_cast<float4*>(dst + 4) = r1;
}

// ---------------------------------------------------------------------------
extern "C" void kernel_launch(void* const* d_in, const int* in_sizes, int n_in,
                              void* d_out, int out_size, void* d_ws, size_t ws_size,
                              hipStream_t stream)
{
    const float* x      = (const float*)d_in[0];
    const float* qkv_w  = (const float*)d_in[1];
    const float* qkv_b  = (const float*)d_in[2];
    const float* rpb    = (const float*)d_in[3];
    const float* proj_w = (const float*)d_in[4];
    const float* proj_b = (const float*)d_in[5];
    float* out = (float*)d_out;
    float* ws  = (float*)d_ws;

    // ws layout: q | k | v  (each QKV_STRIDE floats, 19.3 MB total)
    float* qbuf = ws;
    float* kbuf = ws + (size_t)QKV_STRIDE;
    float* vbuf = ws + (size_t)2 * QKV_STRIDE;
    // d_out doubles as attention-output scratch; proj blocks read only their
    // own 32 rows (full K) during staging, then write the same rows -> no
    // cross-block hazard (grid.y == 1, full 128-col tile per block).
    float* att = out;

    // 1) QKV projection: [12544,128] @ [384,128]^T, scatter into q/k/v
    //    tile 64x128 (MI=8, NJ=4), 588 blocks x 4 waves
    gemm_k<0, 8, 4><<<dim3(MROWS / 64, 3), dim3(256), 0, stream>>>(x, qkv_w, qkv_b, qbuf);

    // 2) neighborhood attention: 784 blocks x 4 waves
    natten_k<<<dim3(49, 4, 4), dim3(256), 0, stream>>>(qbuf, kbuf, vbuf, rpb, att);

    // 3) output projection: [12544,128] @ [128,128]^T (in-place on d_out)
    //    tile 32x128 (MI=4, NJ=4), 392 blocks x 4 waves
    gemm_k<1, 4, 4><<<dim3(MROWS / 32, 1), dim3(256), 0, stream>>>(att, proj_w, proj_b, out);
}

// Round 3
// 47.240 us; speedup vs baseline: 2.6169x; 1.8155x over previous
//
#include <hip/hip_runtime.h>

#define NPIX   3136        // 56*56
#define MROWS  12544       // 4*3136
#define QKV_STRIDE 1605632 // MROWS*128 floats per q/k/v buffer
#define SCALE  0.17677669529663687f  // 32^-0.5

typedef __attribute__((ext_vector_type(8))) _Float16 half8;
typedef __attribute__((ext_vector_type(4))) float    f32x4;

// sum across each aligned quad of 4 lanes via DPP quad_perm
__device__ __forceinline__ float quad_reduce_sum(float x) {
    x += __int_as_float(__builtin_amdgcn_mov_dpp(__float_as_int(x), 0xB1, 0xF, 0xF, true));
    x += __int_as_float(__builtin_amdgcn_mov_dpp(__float_as_int(x), 0x4E, 0xF, 0xF, true));
    return x;
}

// ---------------------------------------------------------------------------
// MFMA GEMM: out = A[M][128] * W[N][128]^T + bias, fp16 inputs / fp32 accum.
// Full K=128 staged once (single barrier). LDS fp16 [rows][128] with XOR
// swizzle k ^ ((r&7)<<3) (half units) -> ds_read_b128 fragment reads hit the
// even-distribution bank floor (8 lanes/quad).
// Fragment maps (16x16x32): A: m=l&15, k=(l>>4)*8+i. B: n=l&15, same k.
// D: col(N)=l&15, row(M)=(l>>4)*4+reg  [m89-verified].
// EPI=0: scatter to q/k/v [which][b*4+head][pix][32]; EPI=1: row-major out.
// ---------------------------------------------------------------------------
template<int EPI, int BM, int BN, int WM, int WN>
__global__ __launch_bounds__(256)
void gemm_mfma(const float* __restrict__ A, const float* __restrict__ W,
               const float* __restrict__ bias, float* __restrict__ out)
{
    constexpr int WTM = BM / WM;     // wave tile rows
    constexpr int WTN = BN / WN;     // wave tile cols
    constexpr int FM  = WTM / 16;    // 16x16 frags per wave (M)
    constexpr int FN  = WTN / 16;    // 16x16 frags per wave (N)
    const int row0 = blockIdx.x * BM;
    const int col0 = blockIdx.y * BN;
    const int t  = threadIdx.x;
    const int w  = t >> 6;
    const int l  = t & 63;
    const int wm = w / WN;
    const int wn = w % WN;

    __shared__ _Float16 Ah[BM * 128];
    __shared__ _Float16 Wh[BN * 128];

    constexpr int AIT = BM * 32 / 256;   // float4s per thread, A tile
    constexpr int WIT = BN * 32 / 256;   // float4s per thread, W tile

    // ---- stage A, W: global fp32 -> fp16 -> swizzled LDS ----
#pragma unroll
    for (int it = 0; it < AIT; ++it) {
        int idx = t + it * 256;
        int r = idx >> 5, k0 = (idx & 31) << 2;
        float4 v = *reinterpret_cast<const float4*>(A + (size_t)(row0 + r) * 128 + k0);
        union { _Float16 h[4]; uint2 u; } cv;
        cv.h[0] = (_Float16)v.x; cv.h[1] = (_Float16)v.y;
        cv.h[2] = (_Float16)v.z; cv.h[3] = (_Float16)v.w;
        *reinterpret_cast<uint2*>(&Ah[r * 128 + (k0 ^ ((r & 7) << 3))]) = cv.u;
    }
#pragma unroll
    for (int it = 0; it < WIT; ++it) {
        int idx = t + it * 256;
        int r = idx >> 5, k0 = (idx & 31) << 2;
        float4 v = *reinterpret_cast<const float4*>(W + (size_t)(col0 + r) * 128 + k0);
        union { _Float16 h[4]; uint2 u; } cv;
        cv.h[0] = (_Float16)v.x; cv.h[1] = (_Float16)v.y;
        cv.h[2] = (_Float16)v.z; cv.h[3] = (_Float16)v.w;
        *reinterpret_cast<uint2*>(&Wh[r * 128 + (k0 ^ ((r & 7) << 3))]) = cv.u;
    }
    __syncthreads();

    f32x4 acc[FM][FN];
#pragma unroll
    for (int mf = 0; mf < FM; ++mf)
#pragma unroll
        for (int nf = 0; nf < FN; ++nf) acc[mf][nf] = (f32x4){0.f, 0.f, 0.f, 0.f};

#pragma unroll
    for (int ks = 0; ks < 4; ++ks) {
        const int kb = ks * 32 + ((l >> 4) << 3);
        half8 a[FM], b[FN];
#pragma unroll
        for (int mf = 0; mf < FM; ++mf) {
            int m = wm * WTM + mf * 16 + (l & 15);
            a[mf] = *reinterpret_cast<const half8*>(&Ah[m * 128 + (kb ^ ((m & 7) << 3))]);
        }
#pragma unroll
        for (int nf = 0; nf < FN; ++nf) {
            int n = wn * WTN + nf * 16 + (l & 15);
            b[nf] = *reinterpret_cast<const half8*>(&Wh[n * 128 + (kb ^ ((n & 7) << 3))]);
        }
#pragma unroll
        for (int mf = 0; mf < FM; ++mf)
#pragma unroll
            for (int nf = 0; nf < FN; ++nf)
                acc[mf][nf] = __builtin_amdgcn_mfma_f32_16x16x32_f16(
                    a[mf], b[nf], acc[mf][nf], 0, 0, 0);
    }

    // ---- epilogue ----
#pragma unroll
    for (int mf = 0; mf < FM; ++mf) {
#pragma unroll
        for (int nf = 0; nf < FN; ++nf) {
#pragma unroll
            for (int r = 0; r < 4; ++r) {
                int row = row0 + wm * WTM + mf * 16 + ((l >> 4) << 2) + r;
                int col = col0 + wn * WTN + nf * 16 + (l & 15);
                float val = acc[mf][nf][r] + bias[col];
                if (EPI == 1) {
                    out[(size_t)row * 128 + col] = val;
                } else {
                    int b_  = row / NPIX;
                    int pix = row - b_ * NPIX;
                    int which = col >> 7;          // 0=q 1=k 2=v
                    int head  = (col & 127) >> 5;
                    int d     = col & 31;
                    out[(size_t)which * QKV_STRIDE +
                        ((size_t)(b_ * 4 + head) * NPIX + pix) * 32 + d] = val;
                }
            }
        }
    }
}

// ---------------------------------------------------------------------------
// Neighborhood attention (unchanged from round 2): 256-thread block per
// (8x8 pixel tile, head, batch); 4 lanes per pixel, 8-float d-slice each,
// quad logit reduce via DPP; K then V staged in swizzled LDS.
// ---------------------------------------------------------------------------
__global__ __launch_bounds__(256)
void natten_k(const float* __restrict__ qb, const float* __restrict__ kb,
              const float* __restrict__ vb, const float* __restrict__ rpb,
              float* __restrict__ att)
{
    const int tile = blockIdx.x;          // 0..48
    const int h    = blockIdx.y;          // 0..3
    const int b    = blockIdx.z;          // 0..3
    const int ti = (tile / 7) * 8;
    const int tj = (tile % 7) * 8;
    const int t   = threadIdx.x;
    const int sub = t & 3;                // d-slice owner within the quad
    const int pl  = t >> 2;               // 0..63 local pixel
    const int pi  = pl >> 3;
    const int pj  = pl & 7;

    __shared__ float kvs[196 * 32];       // 25088 B, K then V

    const size_t hb = (size_t)(b * 4 + h) * NPIX * 32;
    const float* kbase = kb + hb;
    const float* vbase = vb + hb;

    // ---- stage K ----
    for (int e = t; e < 196 * 8; e += 256) {
        int p  = e >> 3;
        int d0 = (e & 7) << 2;
        int wi = p / 14;
        int wj = p - wi * 14;
        int gi = ti - 3 + wi;
        int gj = tj - 3 + wj;
        bool ok = ((unsigned)gi < 56u) && ((unsigned)gj < 56u);
        float4 kv = make_float4(0.f, 0.f, 0.f, 0.f);
        if (ok) kv = *reinterpret_cast<const float4*>(kbase + (gi * 56 + gj) * 32 + d0);
        *reinterpret_cast<float4*>(&kvs[p * 32 + (d0 ^ ((p & 7) << 2))]) = kv;
    }

    // ---- load this lane's q d-slice while K staging is in flight ----
    const int pix = (ti + pi) * 56 + (tj + pj);
    const float* qsrc = qb + hb + (size_t)pix * 32 + sub * 8;
    float4 q0 = *reinterpret_cast<const float4*>(qsrc);
    float4 q1 = *reinterpret_cast<const float4*>(qsrc + 4);

    __syncthreads();

    // ---- QK^T + bias ----
    const float* bias = rpb + h * 169;
    const int d0a = sub * 8;
    const int d0b = sub * 8 + 4;
    float logits[49];
    float m = -1e30f;
#pragma unroll
    for (int ki = 0; ki < 7; ++ki) {
#pragma unroll
        for (int kj = 0; kj < 7; ++kj) {
            int nb   = (pi + ki) * 14 + (pj + kj);
            int base = nb * 32;
            int swx  = (nb & 7) << 2;
            float4 k0 = *reinterpret_cast<const float4*>(&kvs[base + (d0a ^ swx)]);
            float4 k1 = *reinterpret_cast<const float4*>(&kvs[base + (d0b ^ swx)]);
            float s = q0.x * k0.x + q0.y * k0.y + q0.z * k0.z + q0.w * k0.w
                    + q1.x * k1.x + q1.y * k1.y + q1.z * k1.z + q1.w * k1.w;
            s = quad_reduce_sum(s);           // full 32-d dot, all 4 lanes
            float lg = s * SCALE + bias[(ki + 3) * 13 + (kj + 3)];
            logits[ki * 7 + kj] = lg;
            m = fmaxf(m, lg);
        }
    }

    // ---- softmax (redundant per quad lane; cheap) ----
    float sum = 0.f;
#pragma unroll
    for (int n = 0; n < 49; ++n) {
        float e = __expf(logits[n] - m);
        logits[n] = e;
        sum += e;
    }
    float inv = 1.f / sum;

    // ---- stage V into the same LDS ----
    __syncthreads();   // everyone done reading K
    for (int e = t; e < 196 * 8; e += 256) {
        int p  = e >> 3;
        int d0 = (e & 7) << 2;
        int wi = p / 14;
        int wj = p - wi * 14;
        int gi = ti - 3 + wi;
        int gj = tj - 3 + wj;
        bool ok = ((unsigned)gi < 56u) && ((unsigned)gj < 56u);
        float4 vv = make_float4(0.f, 0.f, 0.f, 0.f);
        if (ok) vv = *reinterpret_cast<const float4*>(vbase + (gi * 56 + gj) * 32 + d0);
        *reinterpret_cast<float4*>(&kvs[p * 32 + (d0 ^ ((p & 7) << 2))]) = vv;
    }
    __syncthreads();

    // ---- P·V (each lane accumulates its own 8-float d-slice) ----
    float4 o0 = make_float4(0.f, 0.f, 0.f, 0.f);
    float4 o1 = make_float4(0.f, 0.f, 0.f, 0.f);
#pragma unroll
    for (int ki = 0; ki < 7; ++ki) {
#pragma unroll
        for (int kj = 0; kj < 7; ++kj) {
            int nb   = (pi + ki) * 14 + (pj + kj);
            int base = nb * 32;
            int swx  = (nb & 7) << 2;
            float w = logits[ki * 7 + kj];
            float4 v0 = *reinterpret_cast<const float4*>(&kvs[base + (d0a ^ swx)]);
            float4 v1 = *reinterpret_cast<const float4*>(&kvs[base + (d0b ^ swx)]);
            o0.x += w * v0.x; o0.y += w * v0.y; o0.z += w * v0.z; o0.w += w * v0.w;
            o1.x += w * v1.x; o1.y += w * v1.y; o1.z += w * v1.z; o1.w += w * v1.w;
        }
    }

    // ---- write attention output, layout [b][pix][h*32+d] for the proj GEMM ----
    float* dst = att + ((size_t)b * NPIX + pix) * 128 + h * 32 + sub * 8;
    float4 r0, r1;
    r0.x = o0.x * inv; r0.y = o0.y * inv; r0.z = o0.z * inv; r0.w = o0.w * inv;
    r1.x = o1.x * inv; r1.y = o1.y * inv; r1.z = o1.z * inv; r1.w = o1.w * inv;
    *reinterpret_cast<float4*>(dst)     = r0;
    *reinterpret_cast<float4*>(dst + 4) = r1;
}

// ---------------------------------------------------------------------------
extern "C" void kernel_launch(void* const* d_in, const int* in_sizes, int n_in,
                              void* d_out, int out_size, void* d_ws, size_t ws_size,
                              hipStream_t stream)
{
    const float* x      = (const float*)d_in[0];
    const float* qkv_w  = (const float*)d_in[1];
    const float* qkv_b  = (const float*)d_in[2];
    const float* rpb    = (const float*)d_in[3];
    const float* proj_w = (const float*)d_in[4];
    const float* proj_b = (const float*)d_in[5];
    float* out = (float*)d_out;
    float* ws  = (float*)d_ws;

    // ws layout: q | k | v  (each QKV_STRIDE floats, 19.3 MB total)
    float* qbuf = ws;
    float* kbuf = ws + (size_t)QKV_STRIDE;
    float* vbuf = ws + (size_t)2 * QKV_STRIDE;
    // d_out doubles as attention-output scratch; proj blocks stage (read)
    // only their own 16 rows across the full 128-col width before writing
    // the same rows -> no cross-block hazard (grid.y == 1).
    float* att = out;

    // 1) QKV projection: [12544,128] @ [384,128]^T -> scatter q/k/v
    //    BM=64 BN=128, 2x2 waves (wave tile 32x64, 32 MFMA), grid 196x3
    gemm_mfma<0, 64, 128, 2, 2><<<dim3(196, 3), dim3(256), 0, stream>>>(
        x, qkv_w, qkv_b, qbuf);

    // 2) neighborhood attention: 784 blocks x 4 waves
    natten_k<<<dim3(49, 4, 4), dim3(256), 0, stream>>>(qbuf, kbuf, vbuf, rpb, att);

    // 3) output projection: [12544,128] @ [128,128]^T (in-place on d_out)
    //    BM=16 BN=128, 1x4 waves (wave tile 16x32, 8 MFMA), grid 784
    gemm_mfma<1, 16, 128, 1, 4><<<dim3(784, 1), dim3(256), 0, stream>>>(
        att, proj_w, proj_b, out);
}

// Round 4
// 34.936 us; speedup vs baseline: 3.5385x; 1.3522x over previous
//
#include <hip/hip_runtime.h>

#define NPIX   3136        // 56*56
#define MROWS  12544       // 4*3136
#define QKV_STRIDE 1605632 // MROWS*128 halves per q/k/v buffer
#define SCALE  0.17677669529663687f  // 32^-0.5

typedef __attribute__((ext_vector_type(8))) _Float16 half8;
typedef __attribute__((ext_vector_type(2))) _Float16 v2h;
typedef __attribute__((ext_vector_type(4))) float    f32x4;

#if defined(__has_builtin)
#if __has_builtin(__builtin_amdgcn_fdot2)
#define HAS_FDOT2 1
#endif
#endif

// sum across each aligned quad of 4 lanes via DPP quad_perm
__device__ __forceinline__ float quad_reduce_sum(float x) {
    x += __int_as_float(__builtin_amdgcn_mov_dpp(__float_as_int(x), 0xB1, 0xF, 0xF, true));
    x += __int_as_float(__builtin_amdgcn_mov_dpp(__float_as_int(x), 0x4E, 0xF, 0xF, true));
    return x;
}

// 8-wide fp16 dot with fp32 accumulate (v_dot2_f32_f16 x4)
__device__ __forceinline__ float dot8h(half8 a, half8 b, float acc) {
#ifdef HAS_FDOT2
    union { half8 v; v2h p[4]; } ua, ub;
    ua.v = a; ub.v = b;
    acc = __builtin_amdgcn_fdot2(ua.p[0], ub.p[0], acc, false);
    acc = __builtin_amdgcn_fdot2(ua.p[1], ub.p[1], acc, false);
    acc = __builtin_amdgcn_fdot2(ua.p[2], ub.p[2], acc, false);
    acc = __builtin_amdgcn_fdot2(ua.p[3], ub.p[3], acc, false);
#else
#pragma unroll
    for (int i = 0; i < 8; ++i) acc += (float)a[i] * (float)b[i];
#endif
    return acc;
}

// ---------------------------------------------------------------------------
// MFMA GEMM: out = A[M][128] * W[N][128]^T + bias, fp16 MFMA / fp32 accum.
// Full K=128 staged once. LDS fp16 [rows][128] with XOR swizzle
// k ^ ((r&7)<<3) (half units) -> fragment ds_read_b128 at bank floor.
// Fragment maps (16x16x32): A: m=l&15, k=(l>>4)*8+i; B mirrored;
// D: col=l&15, row=(l>>4)*4+reg  [m89-verified, validated by round 3 pass].
// EPI=0: A fp32, scatter fp16 q/k/v [which][b*4+head][pix][32]
// EPI=1: A fp16 (att), write fp32 out[row][128]
// ---------------------------------------------------------------------------
template<int EPI, int BM, int BN, int WM, int WN>
__global__ __launch_bounds__(256)
void gemm_mfma(const void* __restrict__ Av, const float* __restrict__ W,
               const float* __restrict__ bias, void* __restrict__ outv)
{
    constexpr int WTM = BM / WM;
    constexpr int WTN = BN / WN;
    constexpr int FM  = WTM / 16;
    constexpr int FN  = WTN / 16;
    const int row0 = blockIdx.x * BM;
    const int col0 = blockIdx.y * BN;
    const int t  = threadIdx.x;
    const int w  = t >> 6;
    const int l  = t & 63;
    const int wm = w / WN;
    const int wn = w % WN;

    __shared__ _Float16 Ah[BM * 128];
    __shared__ _Float16 Wh[BN * 128];

    // ---- stage A ----
    if (EPI == 0) {
        const float* A = (const float*)Av;
        constexpr int AIT = BM * 32 / 256;          // float4s per thread
#pragma unroll
        for (int it = 0; it < AIT; ++it) {
            int idx = t + it * 256;
            int r = idx >> 5, k0 = (idx & 31) << 2; // k0 in halves (4-half granule)
            float4 v = *reinterpret_cast<const float4*>(A + (size_t)(row0 + r) * 128 + k0);
            union { _Float16 h[4]; uint2 u; } cv;
            cv.h[0] = (_Float16)v.x; cv.h[1] = (_Float16)v.y;
            cv.h[2] = (_Float16)v.z; cv.h[3] = (_Float16)v.w;
            *reinterpret_cast<uint2*>(&Ah[r * 128 + (k0 ^ ((r & 7) << 3))]) = cv.u;
        }
    } else {
        const _Float16* A = (const _Float16*)Av;
        constexpr int AIT = BM * 16 / 256;          // half8s per thread
#pragma unroll
        for (int it = 0; it < AIT; ++it) {
            int idx = t + it * 256;
            int r = idx >> 4, k0 = (idx & 15) << 3; // k0 in halves (8-half granule)
            half8 v = *reinterpret_cast<const half8*>(A + (size_t)(row0 + r) * 128 + k0);
            *reinterpret_cast<half8*>(&Ah[r * 128 + (k0 ^ ((r & 7) << 3))]) = v;
        }
    }
    // ---- stage W (fp32 global -> fp16 LDS) ----
    {
        constexpr int WIT = BN * 32 / 256;
#pragma unroll
        for (int it = 0; it < WIT; ++it) {
            int idx = t + it * 256;
            int r = idx >> 5, k0 = (idx & 31) << 2;
            float4 v = *reinterpret_cast<const float4*>(W + (size_t)(col0 + r) * 128 + k0);
            union { _Float16 h[4]; uint2 u; } cv;
            cv.h[0] = (_Float16)v.x; cv.h[1] = (_Float16)v.y;
            cv.h[2] = (_Float16)v.z; cv.h[3] = (_Float16)v.w;
            *reinterpret_cast<uint2*>(&Wh[r * 128 + (k0 ^ ((r & 7) << 3))]) = cv.u;
        }
    }
    __syncthreads();

    f32x4 acc[FM][FN];
#pragma unroll
    for (int mf = 0; mf < FM; ++mf)
#pragma unroll
        for (int nf = 0; nf < FN; ++nf) acc[mf][nf] = (f32x4){0.f, 0.f, 0.f, 0.f};

#pragma unroll
    for (int ks = 0; ks < 4; ++ks) {
        const int kb = ks * 32 + ((l >> 4) << 3);
        half8 a[FM], b[FN];
#pragma unroll
        for (int mf = 0; mf < FM; ++mf) {
            int m = wm * WTM + mf * 16 + (l & 15);
            a[mf] = *reinterpret_cast<const half8*>(&Ah[m * 128 + (kb ^ ((m & 7) << 3))]);
        }
#pragma unroll
        for (int nf = 0; nf < FN; ++nf) {
            int n = wn * WTN + nf * 16 + (l & 15);
            b[nf] = *reinterpret_cast<const half8*>(&Wh[n * 128 + (kb ^ ((n & 7) << 3))]);
        }
#pragma unroll
        for (int mf = 0; mf < FM; ++mf)
#pragma unroll
            for (int nf = 0; nf < FN; ++nf)
                acc[mf][nf] = __builtin_amdgcn_mfma_f32_16x16x32_f16(
                    a[mf], b[nf], acc[mf][nf], 0, 0, 0);
    }

    // ---- epilogue ----
#pragma unroll
    for (int mf = 0; mf < FM; ++mf) {
#pragma unroll
        for (int nf = 0; nf < FN; ++nf) {
#pragma unroll
            for (int r = 0; r < 4; ++r) {
                int row = row0 + wm * WTM + mf * 16 + ((l >> 4) << 2) + r;
                int col = col0 + wn * WTN + nf * 16 + (l & 15);
                float val = acc[mf][nf][r] + bias[col];
                if (EPI == 1) {
                    ((float*)outv)[(size_t)row * 128 + col] = val;
                } else {
                    int b_  = row / NPIX;
                    int pix = row - b_ * NPIX;
                    int which = col >> 7;          // 0=q 1=k 2=v
                    int head  = (col & 127) >> 5;
                    int d     = col & 31;
                    ((_Float16*)outv)[(size_t)which * QKV_STRIDE +
                        ((size_t)(b_ * 4 + head) * NPIX + pix) * 32 + d] = (_Float16)val;
                }
            }
        }
    }
}

// ---------------------------------------------------------------------------
// Neighborhood attention, fp16 data / fp32 accum.
// 256-thread block per (8x8 pixel tile, head, batch); 4 lanes per pixel,
// each owning an 8-half d-slice (one ds_read_b128 per neighbor); quad logit
// reduce via DPP. K then V staged in the same fp16 LDS buffer [196][32]
// (granule = nb*4+sub spreads evenly over all 8 bank-quads -> no swizzle).
// OOB neighbors stay zero -> logit = bias only, kept in softmax (matches
// reference zero-padding). launch_bounds(,3): VGPR<=170 -> 3 waves/SIMD,
// matching the grid's 3.06 (round-2's VGPR=256 capped at 2).
// ---------------------------------------------------------------------------
__global__ __launch_bounds__(256, 3)
void natten_k(const _Float16* __restrict__ qb, const _Float16* __restrict__ kb,
              const _Float16* __restrict__ vb, const float* __restrict__ rpb,
              _Float16* __restrict__ att)
{
    const int tile = blockIdx.x;          // 0..48
    const int h    = blockIdx.y;          // 0..3
    const int b    = blockIdx.z;          // 0..3
    const int ti = (tile / 7) * 8;
    const int tj = (tile % 7) * 8;
    const int t   = threadIdx.x;
    const int sub = t & 3;                // d-slice owner within the quad
    const int pl  = t >> 2;               // 0..63 local pixel
    const int pi  = pl >> 3;
    const int pj  = pl & 7;

    __shared__ _Float16 kvs[196 * 32];    // 12544 B, K then V

    const size_t hb = (size_t)(b * 4 + h) * NPIX * 32;
    const _Float16* kbase = kb + hb;
    const _Float16* vbase = vb + hb;

    // ---- stage K: 784 16B-granules over 256 threads ----
    for (int e = t; e < 196 * 4; e += 256) {
        int p = e >> 2;
        int g = e & 3;
        int wi = p / 14;
        int wj = p - wi * 14;
        int gi = ti - 3 + wi;
        int gj = tj - 3 + wj;
        half8 kv = (half8){0,0,0,0,0,0,0,0};
        if (((unsigned)gi < 56u) && ((unsigned)gj < 56u))
            kv = *reinterpret_cast<const half8*>(kbase + (gi * 56 + gj) * 32 + g * 8);
        *reinterpret_cast<half8*>(&kvs[p * 32 + g * 8]) = kv;
    }

    // ---- load this lane's q d-slice while K staging is in flight ----
    const int pix = (ti + pi) * 56 + (tj + pj);
    half8 qv = *reinterpret_cast<const half8*>(qb + hb + (size_t)pix * 32 + sub * 8);

    __syncthreads();

    // ---- QK^T + bias ----
    const float* bias = rpb + h * 169;
    float logits[49];
    float m = -1e30f;
#pragma unroll
    for (int ki = 0; ki < 7; ++ki) {
#pragma unroll
        for (int kj = 0; kj < 7; ++kj) {
            int nb = (pi + ki) * 14 + (pj + kj);
            half8 kk = *reinterpret_cast<const half8*>(&kvs[nb * 32 + sub * 8]);
            float s = dot8h(qv, kk, 0.f);
            s = quad_reduce_sum(s);       // full 32-d dot in all 4 lanes
            float lg = s * SCALE + bias[(ki + 3) * 13 + (kj + 3)];
            logits[ki * 7 + kj] = lg;
            m = fmaxf(m, lg);
        }
    }

    // ---- softmax (redundant per quad lane; cheap) ----
    float sum = 0.f;
#pragma unroll
    for (int n = 0; n < 49; ++n) {
        float e = __expf(logits[n] - m);
        logits[n] = e;
        sum += e;
    }
    float inv = 1.f / sum;

    // ---- stage V into the same LDS ----
    __syncthreads();   // everyone done reading K
    for (int e = t; e < 196 * 4; e += 256) {
        int p = e >> 2;
        int g = e & 3;
        int wi = p / 14;
        int wj = p - wi * 14;
        int gi = ti - 3 + wi;
        int gj = tj - 3 + wj;
        half8 vv = (half8){0,0,0,0,0,0,0,0};
        if (((unsigned)gi < 56u) && ((unsigned)gj < 56u))
            vv = *reinterpret_cast<const half8*>(vbase + (gi * 56 + gj) * 32 + g * 8);
        *reinterpret_cast<half8*>(&kvs[p * 32 + g * 8]) = vv;
    }
    __syncthreads();

    // ---- P·V (fp32 accum, v_fma_mix on fp16 V) ----
    float o[8] = {0.f, 0.f, 0.f, 0.f, 0.f, 0.f, 0.f, 0.f};
#pragma unroll
    for (int ki = 0; ki < 7; ++ki) {
#pragma unroll
        for (int kj = 0; kj < 7; ++kj) {
            int nb = (pi + ki) * 14 + (pj + kj);
            half8 vv = *reinterpret_cast<const half8*>(&kvs[nb * 32 + sub * 8]);
            float wgt = logits[ki * 7 + kj];
#pragma unroll
            for (int i = 0; i < 8; ++i)
                o[i] += wgt * (float)vv[i];
        }
    }

    // ---- write fp16 att, layout [b][pix][h*32+d] for the proj GEMM ----
    _Float16* dst = att + ((size_t)b * NPIX + pix) * 128 + h * 32 + sub * 8;
    half8 r;
#pragma unroll
    for (int i = 0; i < 8; ++i) r[i] = (_Float16)(o[i] * inv);
    *reinterpret_cast<half8*>(dst) = r;
}

// ---------------------------------------------------------------------------
extern "C" void kernel_launch(void* const* d_in, const int* in_sizes, int n_in,
                              void* d_out, int out_size, void* d_ws, size_t ws_size,
                              hipStream_t stream)
{
    const float* x      = (const float*)d_in[0];
    const float* qkv_w  = (const float*)d_in[1];
    const float* qkv_b  = (const float*)d_in[2];
    const float* rpb    = (const float*)d_in[3];
    const float* proj_w = (const float*)d_in[4];
    const float* proj_b = (const float*)d_in[5];
    float* out = (float*)d_out;

    // ws layout (fp16): q | k | v | att  (3.2 MB each, 12.8 MB total)
    _Float16* qbuf = (_Float16*)d_ws;
    _Float16* kbuf = qbuf + (size_t)QKV_STRIDE;
    _Float16* vbuf = kbuf + (size_t)QKV_STRIDE;
    _Float16* att  = vbuf + (size_t)QKV_STRIDE;

    // 1) QKV projection: [12544,128] @ [384,128]^T -> fp16 q/k/v scatter
    //    BM=64 BN=128, 2x2 waves, grid 196x3
    gemm_mfma<0, 64, 128, 2, 2><<<dim3(196, 3), dim3(256), 0, stream>>>(
        x, qkv_w, qkv_b, qbuf);

    // 2) neighborhood attention: 784 blocks x 4 waves, fp16 in/out
    natten_k<<<dim3(49, 4, 4), dim3(256), 0, stream>>>(qbuf, kbuf, vbuf, rpb, att);

    // 3) output projection: [12544,128] @ [128,128]^T, fp16 A -> fp32 out
    //    BM=16 BN=128, 1x4 waves, grid 784
    gemm_mfma<1, 16, 128, 1, 4><<<dim3(784, 1), dim3(256), 0, stream>>>(
        att, proj_w, proj_b, out);
}